// Round 11
// baseline (263.743 us; speedup 1.0000x reference)
//
#include <hip/hip_runtime.h>
#include <math.h>
#include <stdint.h>

#define NA 32          // N_AGENTS
#define SD 2048        // STATE_DIM
#define BT 2048        // B = BS*T
#define NFRG 144       // col frags (2304 padded cols / 16); 128 agent + 12 tail + 4 pad

typedef float floatx4 __attribute__((ext_vector_type(4)));
typedef short bf16x8  __attribute__((ext_vector_type(8)));

__device__ __forceinline__ unsigned short f2bf(float f) {
    union { float f; uint32_t u; } v; v.f = f;
    uint32_t r = v.u + 0x7FFFu + ((v.u >> 16) & 1u);
    return (unsigned short)(r >> 16);
}

// ---- fragment layouts ----
// A-frag (stA):  elem((bt*64+kc)*512 + (quad*16+l16)*8 + j) = st[bt*16+l16][kc*32+quad*8+j]
// B-frag (Wswz): elem(((i*NFRG+f)*2+h)*512 + (quad*16+l16)*8 + j) = W[n=f*16+l16][k=i*64+h*32+quad*8+j]
// C-frag (Ycn, f32): elem((bt*NFRG+f)*256 + (quad*16+l16)*4 + r) = -Y[bt*16+quad*4+r][f*16+l16]

// ---------------- K0a: st -> A-fragment-order bf16 (coalesced writes) ----
__global__ __launch_bounds__(256) void k0_ast(const float* __restrict__ st,
                                              unsigned short* __restrict__ stA) {
    const int t  = threadIdx.x;
    const int kc = blockIdx.x * 4 + (t >> 6);   // 0..63
    const int bt = blockIdx.y;                  // 0..127
    const int l  = t & 63;
    const int quad = l >> 4, l16 = l & 15;
    const float* src = st + (size_t)(bt * 16 + l16) * SD + kc * 32 + quad * 8;
    float4 v0 = *(const float4*)(src);
    float4 v1 = *(const float4*)(src + 4);
    ushort4 o0, o1;
    o0.x = f2bf(v0.x); o0.y = f2bf(v0.y); o0.z = f2bf(v0.z); o0.w = f2bf(v0.w);
    o1.x = f2bf(v1.x); o1.y = f2bf(v1.y); o1.z = f2bf(v1.z); o1.w = f2bf(v1.w);
    unsigned short* dst = stA + ((size_t)bt * 64 + kc) * 512 + l * 8;
    *(ushort4*)(dst)     = o0;
    *(ushort4*)(dst + 4) = o1;
}

// ------- K0b: weights -> B-frag order (coalesced writes) + bias fold ------
__global__ __launch_bounds__(256) void k0_wswz(const float* __restrict__ Ww1,
                                               const float* __restrict__ Wwf,
                                               const float* __restrict__ Wb1,
                                               const float* __restrict__ Wv1,
                                               const float* __restrict__ bw1,
                                               const float* __restrict__ bwf,
                                               const float* __restrict__ bb1,
                                               const float* __restrict__ bv1,
                                               unsigned short* __restrict__ Wswz,
                                               float* __restrict__ bcat) {
    const int t = threadIdx.x;
    const int i = blockIdx.y;                   // k-chunk 0..31
    const int f = blockIdx.x * 2 + (t >> 7);    // frag 0..143
    const int h = (t >> 6) & 1;
    const int l = t & 63;
    const int quad = l >> 4, l16 = l & 15;
    const int n = f * 16 + l16;

    const float* src; int ld, nr = 0;
    if (f < 128)      { src = Ww1; ld = 2048; nr = n; }
    else if (f < 132) { src = Wwf; ld = 64;   nr = n - 2048; }
    else if (f < 136) { src = Wb1; ld = 64;   nr = n - 2112; }
    else if (f < 140) { src = Wv1; ld = 64;   nr = n - 2176; }
    else              { src = nullptr; ld = 64; }

    const int k0 = i * 64 + h * 32 + quad * 8;
    unsigned short vals[8];
    #pragma unroll
    for (int j = 0; j < 8; j++)
        vals[j] = src ? f2bf(src[(size_t)(k0 + j) * ld + nr]) : (unsigned short)0;

    unsigned short* dst = Wswz + (((size_t)i * NFRG + f) * 2 + h) * 512 + l * 8;
    ushort4 o0 = {vals[0], vals[1], vals[2], vals[3]};
    ushort4 o1 = {vals[4], vals[5], vals[6], vals[7]};
    *(ushort4*)(dst)     = o0;
    *(ushort4*)(dst + 4) = o1;

    // fold: bias concat (once, by the i==0,h==0,quad==0 lanes)
    if (i == 0 && h == 0 && quad == 0) {
        float bv = 0.f;
        if (f < 128)      bv = bw1[n];
        else if (f < 132) bv = bwf[n - 2048];
        else if (f < 136) bv = bb1[n - 2112];
        else if (f < 140) bv = bv1[n - 2176];
        bcat[n] = bv;
    }
}

// ---------------- K1: Ycn = -(st @ Wcat + bias), fp32 fragment layout -----
// Register-streamed MFMA loop, software-pipelined one iteration.
__global__ __launch_bounds__(256) void k1_gemm(const unsigned short* __restrict__ stA,
                                               const unsigned short* __restrict__ Wswz,
                                               const float* __restrict__ bcat,
                                               float* __restrict__ Ycn)
{
    const int t = threadIdx.x;
    const int m0t = blockIdx.x * 4;   // btile base (64 rows)
    const int n0f = blockIdx.y * 8;   // frag base (128 cols)
    const int wid = t >> 6, lane = t & 63;
    const int wm = wid & 1, wn = wid >> 1;
    const int l16 = lane & 15;

    floatx4 acc[2][4];
    #pragma unroll
    for (int i = 0; i < 2; i++)
        #pragma unroll
        for (int j = 0; j < 4; j++) acc[i][j] = (floatx4)0.f;

    const unsigned short* Ap0 = stA + ((size_t)(m0t + wm * 2 + 0) * 64) * 512 + lane * 8;
    const unsigned short* Ap1 = stA + ((size_t)(m0t + wm * 2 + 1) * 64) * 512 + lane * 8;
    const unsigned short* Bbase = Wswz + ((size_t)(n0f + wn * 4) * 2) * 512 + lane * 8;

    bf16x8 a0c = *(const bf16x8*)(Ap0);
    bf16x8 a1c = *(const bf16x8*)(Ap1);
    bf16x8 bc[4];
    #pragma unroll
    for (int nf = 0; nf < 4; nf++)
        bc[nf] = *(const bf16x8*)(Bbase + (size_t)nf * 1024);

    for (int kc = 0; kc < 63; kc++) {
        const int kn = kc + 1;
        bf16x8 a0n = *(const bf16x8*)(Ap0 + (size_t)kn * 512);
        bf16x8 a1n = *(const bf16x8*)(Ap1 + (size_t)kn * 512);
        const unsigned short* Bp =
            Bbase + ((size_t)(kn >> 1) * NFRG * 2 + (kn & 1)) * 512;
        bf16x8 bn[4];
        #pragma unroll
        for (int nf = 0; nf < 4; nf++)
            bn[nf] = *(const bf16x8*)(Bp + (size_t)nf * 1024);
        #pragma unroll
        for (int nf = 0; nf < 4; nf++) {
            acc[0][nf] = __builtin_amdgcn_mfma_f32_16x16x32_bf16(a0c, bc[nf], acc[0][nf], 0, 0, 0);
            acc[1][nf] = __builtin_amdgcn_mfma_f32_16x16x32_bf16(a1c, bc[nf], acc[1][nf], 0, 0, 0);
        }
        a0c = a0n; a1c = a1n;
        #pragma unroll
        for (int nf = 0; nf < 4; nf++) bc[nf] = bn[nf];
    }
    #pragma unroll
    for (int nf = 0; nf < 4; nf++) {
        acc[0][nf] = __builtin_amdgcn_mfma_f32_16x16x32_bf16(a0c, bc[nf], acc[0][nf], 0, 0, 0);
        acc[1][nf] = __builtin_amdgcn_mfma_f32_16x16x32_bf16(a1c, bc[nf], acc[1][nf], 0, 0, 0);
    }

    #pragma unroll
    for (int mf = 0; mf < 2; mf++)
        #pragma unroll
        for (int nf = 0; nf < 4; nf++) {
            const int f  = n0f + wn * 4 + nf;
            const int bt = m0t + wm * 2 + mf;
            const float bias = bcat[f * 16 + l16];
            floatx4 o;
            #pragma unroll
            for (int r = 0; r < 4; r++) o[r] = -(acc[mf][nf][r] + bias);
            *(floatx4*)(Ycn + ((size_t)bt * NFRG + f) * 256 + lane * 4) = o;
        }
}

// ---------------- K3: q1[i][b] for i=0..32 (i=32 => unmasked q_tot) ------
// Single wave per block, fp32 Ycn direct-to-acc, 1-deep weight prefetch.
// For i==32: P=0, so skip all weight loads/MFMAs; c = -Y gives the
// unmasked mix directly (q_tot lands in q1 row 32).
__global__ __launch_bounds__(64) void k3_q1(
    const unsigned short* __restrict__ stA, const float* __restrict__ qs,
    const unsigned short* __restrict__ Wswz, const float* __restrict__ Wv2,
    const float* __restrict__ bv2, const float* __restrict__ Ycn,
    float* __restrict__ q1)
{
    const int i  = blockIdx.x;        // mask 0..32
    const int bt = blockIdx.y;        // b tile 0..127
    __shared__ float qs_s[16][33];

    const int t = threadIdx.x;        // == lane
    const int quad = t >> 4, l16 = t & 15;

    {
        int b = t >> 2, a0 = (t & 3) * 8;
        const float* src = qs + (size_t)(bt * 16 + b) * NA + a0;
        #pragma unroll
        for (int u = 0; u < 8; u++) qs_s[b][a0 + u] = src[u];
    }
    bf16x8 A0{}, A1{};
    if (i < 32) {
        A0 = *(const bf16x8*)(stA + ((size_t)bt * 64 + 2 * i + 0) * 512 + t * 8);
        A1 = *(const bf16x8*)(stA + ((size_t)bt * 64 + 2 * i + 1) * 512 + t * 8);
    }
    __syncthreads();

    floatx4 hid[4];
    #pragma unroll
    for (int nf = 0; nf < 4; nf++) hid[nf] = (floatx4)0.f;

    const float*          Yb = Ycn  + (size_t)bt * NFRG * 256;
    const unsigned short* Wb = Wswz + (size_t)i * NFRG * 1024;

    if (i < 32) {
        bf16x8 wc_[8];
        {
            const unsigned short* wp = Wb + t * 8;
            #pragma unroll
            for (int nf = 0; nf < 4; nf++) {
                wc_[nf * 2 + 0] = *(const bf16x8*)(wp + (size_t)nf * 1024);
                wc_[nf * 2 + 1] = *(const bf16x8*)(wp + (size_t)nf * 1024 + 512);
            }
        }
        for (int a = 0; a < 32; a++) {
            bf16x8 wn_[8];
            if (a < 31) {
                const unsigned short* wp = Wb + (size_t)((a + 1) * 4) * 1024 + t * 8;
                #pragma unroll
                for (int nf = 0; nf < 4; nf++) {
                    wn_[nf * 2 + 0] = *(const bf16x8*)(wp + (size_t)nf * 1024);
                    wn_[nf * 2 + 1] = *(const bf16x8*)(wp + (size_t)nf * 1024 + 512);
                }
            }
            const float* yp = Yb + (size_t)(a * 4) * 256 + t * 4;
            floatx4 acc[4];
            #pragma unroll
            for (int nf = 0; nf < 4; nf++) acc[nf] = *(const floatx4*)(yp + nf * 256);
            #pragma unroll
            for (int nf = 0; nf < 4; nf++) {
                acc[nf] = __builtin_amdgcn_mfma_f32_16x16x32_bf16(A0, wc_[nf*2+0], acc[nf], 0, 0, 0);
                acc[nf] = __builtin_amdgcn_mfma_f32_16x16x32_bf16(A1, wc_[nf*2+1], acc[nf], 0, 0, 0);
            }
            float qv[4];
            #pragma unroll
            for (int r = 0; r < 4; r++) qv[r] = qs_s[quad * 4 + r][a];
            #pragma unroll
            for (int nf = 0; nf < 4; nf++)
                #pragma unroll
                for (int r = 0; r < 4; r++)
                    hid[nf][r] += qv[r] * fabsf(acc[nf][r]);
            #pragma unroll
            for (int u = 0; u < 8; u++) wc_[u] = wn_[u];
        }
    } else {
        for (int a = 0; a < 32; a++) {
            const float* yp = Yb + (size_t)(a * 4) * 256 + t * 4;
            float qv[4];
            #pragma unroll
            for (int r = 0; r < 4; r++) qv[r] = qs_s[quad * 4 + r][a];
            #pragma unroll
            for (int nf = 0; nf < 4; nf++) {
                floatx4 c = *(const floatx4*)(yp + nf * 256);
                #pragma unroll
                for (int r = 0; r < 4; r++)
                    hid[nf][r] += qv[r] * fabsf(c[r]);
            }
        }
    }

    // tail frags 128..139: wf(0-3) | b1(4-7) | v(8-11)
    floatx4 wff[4], b1f[4], vacc = (floatx4)0.f;
    #pragma unroll
    for (int nft = 0; nft < 12; nft++) {
        const int f = 128 + nft;
        floatx4 c = *(const floatx4*)(Yb + (size_t)f * 256 + t * 4);
        if (i < 32) {
            const unsigned short* wp = Wb + (size_t)f * 1024 + t * 8;
            c = __builtin_amdgcn_mfma_f32_16x16x32_bf16(A0, *(const bf16x8*)(wp),       c, 0, 0, 0);
            c = __builtin_amdgcn_mfma_f32_16x16x32_bf16(A1, *(const bf16x8*)(wp + 512), c, 0, 0, 0);
        }
        if (nft < 4) {
            #pragma unroll
            for (int r = 0; r < 4; r++) wff[nft][r] = fabsf(c[r]);
        } else if (nft < 8) {
            #pragma unroll
            for (int r = 0; r < 4; r++) b1f[nft - 4][r] = -c[r];
        } else {
            float wv2 = Wv2[(nft - 8) * 16 + l16];
            #pragma unroll
            for (int r = 0; r < 4; r++) vacc[r] += fmaxf(-c[r], 0.f) * wv2;
        }
    }

    const float bv2v = bv2[0];
    #pragma unroll
    for (int r = 0; r < 4; r++) {
        float s = vacc[r];
        #pragma unroll
        for (int nf = 0; nf < 4; nf++) {
            float h = hid[nf][r] + b1f[nf][r];
            h = h > 0.f ? h : expm1f(h);
            s += h * wff[nf][r];
        }
        s += __shfl_xor(s, 1); s += __shfl_xor(s, 2);
        s += __shfl_xor(s, 4); s += __shfl_xor(s, 8);
        if (l16 == 0) q1[(size_t)i * BT + bt * 16 + quad * 4 + r] = s + bv2v;
    }
}

// ---------------- K4: wc + final mix — single Ycn pass -------------------
// q_tot comes from q1 row 32 (computed by k3). One weighted pass over Ycn.
__global__ __launch_bounds__(256) void k4_final(
    const float* __restrict__ qs, const float* __restrict__ Ycn,
    const float* __restrict__ q1, const float* __restrict__ Wv2,
    const float* __restrict__ bv2, float* __restrict__ out)
{
    const int bt = blockIdx.x;
    __shared__ float qs_s[16][33];
    __shared__ float qw_s[16][33];
    __shared__ float hidp[4][16][64];
    __shared__ float wfb[16][64], b1b[16][64], vb[16][64];

    const int t = threadIdx.x, w = t >> 6, lane = t & 63;
    const int quad = lane >> 4, l16 = lane & 15;
    const float bv2v = bv2[0];

    {
        int l = t * 2;
        float2 v = *(const float2*)&qs[(size_t)(bt * 16 + (l >> 5)) * NA + (l & 31)];
        qs_s[l >> 5][(l & 31) + 0] = v.x;
        qs_s[l >> 5][(l & 31) + 1] = v.y;
    }
    __syncthreads();

    // wc: thread (w,quad,l16) -> row rr = w*4+quad, agents 2*l16, 2*l16+1
    {
        const int rr = w * 4 + quad;
        float qtv = q1[(size_t)32 * BT + bt * 16 + rr];
        float d0 = fabsf(qtv - q1[(size_t)(2 * l16 + 0) * BT + bt * 16 + rr]);
        float d1 = fabsf(qtv - q1[(size_t)(2 * l16 + 1) * BT + bt * 16 + rr]);
        float ss = d0 * d0 + d1 * d1;
        ss += __shfl_xor(ss, 1); ss += __shfl_xor(ss, 2);
        ss += __shfl_xor(ss, 4); ss += __shfl_xor(ss, 8);
        float inv = 1.f / fmaxf(sqrtf(ss), 1e-12f);
        qw_s[rr][2 * l16 + 0] = qs_s[rr][2 * l16 + 0] * d0 * inv;
        qw_s[rr][2 * l16 + 1] = qs_s[rr][2 * l16 + 1] * d1 * inv;
    }
    __syncthreads();

    const float* Yb = Ycn + (size_t)bt * NFRG * 256;

    // single pass: hid with qs*wc; wave w owns agents w*8..w*8+7
    floatx4 hid[4];
    #pragma unroll
    for (int nf = 0; nf < 4; nf++) hid[nf] = (floatx4)0.f;
    for (int ia = 0; ia < 8; ia++) {
        const int a = w * 8 + ia;
        const float* yp = Yb + (size_t)(a * 4) * 256 + lane * 4;
        float qv[4];
        #pragma unroll
        for (int r = 0; r < 4; r++) qv[r] = qw_s[quad * 4 + r][a];
        #pragma unroll
        for (int nf = 0; nf < 4; nf++) {
            floatx4 c = *(const floatx4*)(yp + nf * 256);   // c = -Y
            #pragma unroll
            for (int r = 0; r < 4; r++) hid[nf][r] += qv[r] * fabsf(c[r]);
        }
    }
    #pragma unroll
    for (int nf = 0; nf < 4; nf++)
        #pragma unroll
        for (int r = 0; r < 4; r++)
            hidp[w][quad * 4 + r][nf * 16 + l16] = hid[nf][r];

    // tail frags: 3 per wave
    #pragma unroll
    for (int fi = 0; fi < 3; fi++) {
        const int nft = w * 3 + fi;
        floatx4 c = *(const floatx4*)(Yb + (size_t)(128 + nft) * 256 + lane * 4);
        const int e = (nft & 3) * 16 + l16;
        #pragma unroll
        for (int r = 0; r < 4; r++) {
            int b = quad * 4 + r;
            if (nft < 4)      wfb[b][e] = fabsf(c[r]);
            else if (nft < 8) b1b[b][e] = -c[r];
            else              vb[b][e]  = fmaxf(-c[r], 0.f) * Wv2[e];
        }
    }
    __syncthreads();

    #pragma unroll
    for (int bb = 0; bb < 4; bb++) {
        int b = w * 4 + bb;
        float h = hidp[0][b][lane] + hidp[1][b][lane]
                + hidp[2][b][lane] + hidp[3][b][lane] + b1b[b][lane];
        h = h > 0.f ? h : expm1f(h);
        float val = h * wfb[b][lane] + vb[b][lane];
        #pragma unroll
        for (int off = 32; off > 0; off >>= 1) val += __shfl_xor(val, off);
        if (lane == 0) out[bt * 16 + b] = val + bv2v;
    }
}

extern "C" void kernel_launch(void* const* d_in, const int* in_sizes, int n_in,
                              void* d_out, int out_size, void* d_ws, size_t ws_size,
                              hipStream_t stream) {
    const float* qs  = (const float*)d_in[0];
    const float* st  = (const float*)d_in[1];
    const float* Ww1 = (const float*)d_in[2];
    const float* bw1 = (const float*)d_in[3];
    const float* Wwf = (const float*)d_in[4];
    const float* bwf = (const float*)d_in[5];
    const float* Wb1 = (const float*)d_in[6];
    const float* bb1 = (const float*)d_in[7];
    const float* Wv1 = (const float*)d_in[8];
    const float* bv1 = (const float*)d_in[9];
    const float* Wv2 = (const float*)d_in[10];
    const float* bv2 = (const float*)d_in[11];
    float* out = (float*)d_out;

    // workspace (~37 MB)
    float* Ycn           = (float*)d_ws;                           // 128*144*256 f32 = 18.87 MB
    unsigned short* stA  = (unsigned short*)(Ycn + (size_t)128 * NFRG * 256); // 8.39 MB
    unsigned short* Wswz = stA + (size_t)SD * SD;                  // 32*144*1024 bf16 = 9.44 MB
    float* bcat          = (float*)(Wswz + (size_t)32 * NFRG * 1024); // 2304 f32
    float* q1v           = bcat + NFRG * 16;                       // 33*2048 f32

    k0_ast <<<dim3(16, 128), 256, 0, stream>>>(st, stA);
    k0_wswz<<<dim3(NFRG / 2, 32), 256, 0, stream>>>(Ww1, Wwf, Wb1, Wv1,
                                                    bw1, bwf, bb1, bv1, Wswz, bcat);

    k1_gemm<<<dim3(BT / 64, NFRG / 8), 256, 0, stream>>>(stA, Wswz, bcat, Ycn);
    k3_q1  <<<dim3(NA + 1, BT / 16), 64, 0, stream>>>(stA, qs, Wswz, Wv2, bv2, Ycn, q1v);
    k4_final<<<BT / 16, 256, 0, stream>>>(qs, Ycn, q1v, Wv2, bv2, out);
}

// Round 12
// 258.398 us; speedup vs baseline: 1.0207x; 1.0207x over previous
//
#include <hip/hip_runtime.h>
#include <math.h>
#include <stdint.h>

#define NA 32          // N_AGENTS
#define SD 2048        // STATE_DIM
#define BT 2048        // B = BS*T
#define NFRG 144       // col frags (2304 padded cols / 16); 128 agent + 12 tail + 4 pad

typedef float floatx4 __attribute__((ext_vector_type(4)));
typedef short bf16x8  __attribute__((ext_vector_type(8)));

__device__ __forceinline__ unsigned short f2bf(float f) {
    union { float f; uint32_t u; } v; v.f = f;
    uint32_t r = v.u + 0x7FFFu + ((v.u >> 16) & 1u);
    return (unsigned short)(r >> 16);
}

// ---- fragment layouts ----
// A-frag (stA):  elem((bt*64+kc)*512 + (quad*16+l16)*8 + j) = st[bt*16+l16][kc*32+quad*8+j]
// B-frag (Wswz): elem(((i*NFRG+f)*2+h)*512 + (quad*16+l16)*8 + j) = W[n=f*16+l16][k=i*64+h*32+quad*8+j]
// C-frag (Ycn, f32): elem((bt*NFRG+f)*256 + (quad*16+l16)*4 + r) = -Y[bt*16+quad*4+r][f*16+l16]

// ---------------- K0a: st -> A-fragment-order bf16 (coalesced writes) ----
__global__ __launch_bounds__(256) void k0_ast(const float* __restrict__ st,
                                              unsigned short* __restrict__ stA) {
    const int t  = threadIdx.x;
    const int kc = blockIdx.x * 4 + (t >> 6);   // 0..63
    const int bt = blockIdx.y;                  // 0..127
    const int l  = t & 63;
    const int quad = l >> 4, l16 = l & 15;
    const float* src = st + (size_t)(bt * 16 + l16) * SD + kc * 32 + quad * 8;
    float4 v0 = *(const float4*)(src);
    float4 v1 = *(const float4*)(src + 4);
    ushort4 o0, o1;
    o0.x = f2bf(v0.x); o0.y = f2bf(v0.y); o0.z = f2bf(v0.z); o0.w = f2bf(v0.w);
    o1.x = f2bf(v1.x); o1.y = f2bf(v1.y); o1.z = f2bf(v1.z); o1.w = f2bf(v1.w);
    unsigned short* dst = stA + ((size_t)bt * 64 + kc) * 512 + l * 8;
    *(ushort4*)(dst)     = o0;
    *(ushort4*)(dst + 4) = o1;
}

// ------- K0b: weights -> B-frag order (coalesced writes) + bias fold ------
__global__ __launch_bounds__(256) void k0_wswz(const float* __restrict__ Ww1,
                                               const float* __restrict__ Wwf,
                                               const float* __restrict__ Wb1,
                                               const float* __restrict__ Wv1,
                                               const float* __restrict__ bw1,
                                               const float* __restrict__ bwf,
                                               const float* __restrict__ bb1,
                                               const float* __restrict__ bv1,
                                               unsigned short* __restrict__ Wswz,
                                               float* __restrict__ bcat) {
    const int t = threadIdx.x;
    const int i = blockIdx.y;                   // k-chunk 0..31
    const int f = blockIdx.x * 2 + (t >> 7);    // frag 0..143
    const int h = (t >> 6) & 1;
    const int l = t & 63;
    const int quad = l >> 4, l16 = l & 15;
    const int n = f * 16 + l16;

    const float* src; int ld, nr = 0;
    if (f < 128)      { src = Ww1; ld = 2048; nr = n; }
    else if (f < 132) { src = Wwf; ld = 64;   nr = n - 2048; }
    else if (f < 136) { src = Wb1; ld = 64;   nr = n - 2112; }
    else if (f < 140) { src = Wv1; ld = 64;   nr = n - 2176; }
    else              { src = nullptr; ld = 64; }

    const int k0 = i * 64 + h * 32 + quad * 8;
    unsigned short vals[8];
    #pragma unroll
    for (int j = 0; j < 8; j++)
        vals[j] = src ? f2bf(src[(size_t)(k0 + j) * ld + nr]) : (unsigned short)0;

    unsigned short* dst = Wswz + (((size_t)i * NFRG + f) * 2 + h) * 512 + l * 8;
    ushort4 o0 = {vals[0], vals[1], vals[2], vals[3]};
    ushort4 o1 = {vals[4], vals[5], vals[6], vals[7]};
    *(ushort4*)(dst)     = o0;
    *(ushort4*)(dst + 4) = o1;

    if (i == 0 && h == 0 && quad == 0) {
        float bv = 0.f;
        if (f < 128)      bv = bw1[n];
        else if (f < 132) bv = bwf[n - 2048];
        else if (f < 136) bv = bb1[n - 2112];
        else if (f < 140) bv = bv1[n - 2176];
        bcat[n] = bv;
    }
}

// ---------------- K1: Ycn = -(st @ Wcat + bias), fp32 fragment layout -----
__global__ __launch_bounds__(256) void k1_gemm(const unsigned short* __restrict__ stA,
                                               const unsigned short* __restrict__ Wswz,
                                               const float* __restrict__ bcat,
                                               float* __restrict__ Ycn)
{
    const int t = threadIdx.x;
    const int m0t = blockIdx.x * 4;   // btile base (64 rows)
    const int n0f = blockIdx.y * 8;   // frag base (128 cols)
    const int wid = t >> 6, lane = t & 63;
    const int wm = wid & 1, wn = wid >> 1;
    const int l16 = lane & 15;

    floatx4 acc[2][4];
    #pragma unroll
    for (int i = 0; i < 2; i++)
        #pragma unroll
        for (int j = 0; j < 4; j++) acc[i][j] = (floatx4)0.f;

    const unsigned short* Ap0 = stA + ((size_t)(m0t + wm * 2 + 0) * 64) * 512 + lane * 8;
    const unsigned short* Ap1 = stA + ((size_t)(m0t + wm * 2 + 1) * 64) * 512 + lane * 8;
    const unsigned short* Bbase = Wswz + ((size_t)(n0f + wn * 4) * 2) * 512 + lane * 8;

    bf16x8 a0c = *(const bf16x8*)(Ap0);
    bf16x8 a1c = *(const bf16x8*)(Ap1);
    bf16x8 bc[4];
    #pragma unroll
    for (int nf = 0; nf < 4; nf++)
        bc[nf] = *(const bf16x8*)(Bbase + (size_t)nf * 1024);

    for (int kc = 0; kc < 63; kc++) {
        const int kn = kc + 1;
        bf16x8 a0n = *(const bf16x8*)(Ap0 + (size_t)kn * 512);
        bf16x8 a1n = *(const bf16x8*)(Ap1 + (size_t)kn * 512);
        const unsigned short* Bp =
            Bbase + ((size_t)(kn >> 1) * NFRG * 2 + (kn & 1)) * 512;
        bf16x8 bn[4];
        #pragma unroll
        for (int nf = 0; nf < 4; nf++)
            bn[nf] = *(const bf16x8*)(Bp + (size_t)nf * 1024);
        #pragma unroll
        for (int nf = 0; nf < 4; nf++) {
            acc[0][nf] = __builtin_amdgcn_mfma_f32_16x16x32_bf16(a0c, bc[nf], acc[0][nf], 0, 0, 0);
            acc[1][nf] = __builtin_amdgcn_mfma_f32_16x16x32_bf16(a1c, bc[nf], acc[1][nf], 0, 0, 0);
        }
        a0c = a0n; a1c = a1n;
        #pragma unroll
        for (int nf = 0; nf < 4; nf++) bc[nf] = bn[nf];
    }
    #pragma unroll
    for (int nf = 0; nf < 4; nf++) {
        acc[0][nf] = __builtin_amdgcn_mfma_f32_16x16x32_bf16(a0c, bc[nf], acc[0][nf], 0, 0, 0);
        acc[1][nf] = __builtin_amdgcn_mfma_f32_16x16x32_bf16(a1c, bc[nf], acc[1][nf], 0, 0, 0);
    }

    #pragma unroll
    for (int mf = 0; mf < 2; mf++)
        #pragma unroll
        for (int nf = 0; nf < 4; nf++) {
            const int f  = n0f + wn * 4 + nf;
            const int bt = m0t + wm * 2 + mf;
            const float bias = bcat[f * 16 + l16];
            floatx4 o;
            #pragma unroll
            for (int r = 0; r < 4; r++) o[r] = -(acc[mf][nf][r] + bias);
            *(floatx4*)(Ycn + ((size_t)bt * NFRG + f) * 256 + lane * 4) = o;
        }
}

// ---------------- K3: q1[i][b] — exact R10 kernel (proven 68 µs) ---------
// Single wave per block, XCD-swizzled grid (x=i), fp32 Ycn direct-to-acc,
// 1-deep weight prefetch. No extra branches: register budget stays ~92.
__global__ __launch_bounds__(64) void k3_q1(
    const unsigned short* __restrict__ stA, const float* __restrict__ qs,
    const unsigned short* __restrict__ Wswz, const float* __restrict__ Wv2,
    const float* __restrict__ bv2, const float* __restrict__ Ycn,
    float* __restrict__ q1)
{
    const int i  = blockIdx.x;        // mask 0..31 (fast dim -> XCD = i%8)
    const int bt = blockIdx.y;        // b tile 0..127
    __shared__ float qs_s[16][33];

    const int t = threadIdx.x;        // == lane
    const int quad = t >> 4, l16 = t & 15;

    {
        int b = t >> 2, a0 = (t & 3) * 8;
        const float* src = qs + (size_t)(bt * 16 + b) * NA + a0;
        #pragma unroll
        for (int u = 0; u < 8; u++) qs_s[b][a0 + u] = src[u];
    }
    bf16x8 A0 = *(const bf16x8*)(stA + ((size_t)bt * 64 + 2 * i + 0) * 512 + t * 8);
    bf16x8 A1 = *(const bf16x8*)(stA + ((size_t)bt * 64 + 2 * i + 1) * 512 + t * 8);
    __syncthreads();

    floatx4 hid[4];
    #pragma unroll
    for (int nf = 0; nf < 4; nf++) hid[nf] = (floatx4)0.f;

    const float*          Yb = Ycn  + (size_t)bt * NFRG * 256;
    const unsigned short* Wb = Wswz + (size_t)i * NFRG * 1024;

    bf16x8 wc_[8];
    {
        const unsigned short* wp = Wb + t * 8;
        #pragma unroll
        for (int nf = 0; nf < 4; nf++) {
            wc_[nf * 2 + 0] = *(const bf16x8*)(wp + (size_t)nf * 1024);
            wc_[nf * 2 + 1] = *(const bf16x8*)(wp + (size_t)nf * 1024 + 512);
        }
    }

    for (int a = 0; a < 32; a++) {
        bf16x8 wn_[8];
        if (a < 31) {
            const unsigned short* wp = Wb + (size_t)((a + 1) * 4) * 1024 + t * 8;
            #pragma unroll
            for (int nf = 0; nf < 4; nf++) {
                wn_[nf * 2 + 0] = *(const bf16x8*)(wp + (size_t)nf * 1024);
                wn_[nf * 2 + 1] = *(const bf16x8*)(wp + (size_t)nf * 1024 + 512);
            }
        }
        const float* yp = Yb + (size_t)(a * 4) * 256 + t * 4;
        floatx4 acc[4];
        #pragma unroll
        for (int nf = 0; nf < 4; nf++) acc[nf] = *(const floatx4*)(yp + nf * 256);
        #pragma unroll
        for (int nf = 0; nf < 4; nf++) {
            acc[nf] = __builtin_amdgcn_mfma_f32_16x16x32_bf16(A0, wc_[nf*2+0], acc[nf], 0, 0, 0);
            acc[nf] = __builtin_amdgcn_mfma_f32_16x16x32_bf16(A1, wc_[nf*2+1], acc[nf], 0, 0, 0);
        }
        float qv[4];
        #pragma unroll
        for (int r = 0; r < 4; r++) qv[r] = qs_s[quad * 4 + r][a];
        #pragma unroll
        for (int nf = 0; nf < 4; nf++)
            #pragma unroll
            for (int r = 0; r < 4; r++)
                hid[nf][r] += qv[r] * fabsf(acc[nf][r]);
        #pragma unroll
        for (int u = 0; u < 8; u++) wc_[u] = wn_[u];
    }

    // tail frags 128..139: wf(0-3) | b1(4-7) | v(8-11)
    floatx4 wff[4], b1f[4], vacc = (floatx4)0.f;
    #pragma unroll
    for (int nft = 0; nft < 12; nft++) {
        const int f = 128 + nft;
        floatx4 c = *(const floatx4*)(Yb + (size_t)f * 256 + t * 4);
        const unsigned short* wp = Wb + (size_t)f * 1024 + t * 8;
        c = __builtin_amdgcn_mfma_f32_16x16x32_bf16(A0, *(const bf16x8*)(wp),       c, 0, 0, 0);
        c = __builtin_amdgcn_mfma_f32_16x16x32_bf16(A1, *(const bf16x8*)(wp + 512), c, 0, 0, 0);
        if (nft < 4) {
            #pragma unroll
            for (int r = 0; r < 4; r++) wff[nft][r] = fabsf(c[r]);
        } else if (nft < 8) {
            #pragma unroll
            for (int r = 0; r < 4; r++) b1f[nft - 4][r] = -c[r];
        } else {
            float wv2 = Wv2[(nft - 8) * 16 + l16];
            #pragma unroll
            for (int r = 0; r < 4; r++) vacc[r] += fmaxf(-c[r], 0.f) * wv2;
        }
    }

    const float bv2v = bv2[0];
    #pragma unroll
    for (int r = 0; r < 4; r++) {
        float s = vacc[r];
        #pragma unroll
        for (int nf = 0; nf < 4; nf++) {
            float h = hid[nf][r] + b1f[nf][r];
            h = h > 0.f ? h : expm1f(h);
            s += h * wff[nf][r];
        }
        s += __shfl_xor(s, 1); s += __shfl_xor(s, 2);
        s += __shfl_xor(s, 4); s += __shfl_xor(s, 8);
        if (l16 == 0) q1[(size_t)i * BT + bt * 16 + quad * 4 + r] = s + bv2v;
    }
}

// ---------------- K3b: q_tot (weight-free mix) -> q1 row 32 --------------
// Single wave per bt; c = -Y directly (P=0 path), no weights, no MFMA.
__global__ __launch_bounds__(64) void k3_qtot(
    const float* __restrict__ qs, const float* __restrict__ Wv2,
    const float* __restrict__ bv2, const float* __restrict__ Ycn,
    float* __restrict__ q1)
{
    const int bt = blockIdx.x;        // b tile 0..127
    __shared__ float qs_s[16][33];

    const int t = threadIdx.x;
    const int quad = t >> 4, l16 = t & 15;

    {
        int b = t >> 2, a0 = (t & 3) * 8;
        const float* src = qs + (size_t)(bt * 16 + b) * NA + a0;
        #pragma unroll
        for (int u = 0; u < 8; u++) qs_s[b][a0 + u] = src[u];
    }
    __syncthreads();

    const float* Yb = Ycn + (size_t)bt * NFRG * 256;

    floatx4 hid[4];
    #pragma unroll
    for (int nf = 0; nf < 4; nf++) hid[nf] = (floatx4)0.f;

    for (int a = 0; a < 32; a++) {
        const float* yp = Yb + (size_t)(a * 4) * 256 + t * 4;
        float qv[4];
        #pragma unroll
        for (int r = 0; r < 4; r++) qv[r] = qs_s[quad * 4 + r][a];
        #pragma unroll
        for (int nf = 0; nf < 4; nf++) {
            floatx4 c = *(const floatx4*)(yp + nf * 256);
            #pragma unroll
            for (int r = 0; r < 4; r++) hid[nf][r] += qv[r] * fabsf(c[r]);
        }
    }

    floatx4 wff[4], b1f[4], vacc = (floatx4)0.f;
    #pragma unroll
    for (int nft = 0; nft < 12; nft++) {
        const int f = 128 + nft;
        floatx4 c = *(const floatx4*)(Yb + (size_t)f * 256 + t * 4);
        if (nft < 4) {
            #pragma unroll
            for (int r = 0; r < 4; r++) wff[nft][r] = fabsf(c[r]);
        } else if (nft < 8) {
            #pragma unroll
            for (int r = 0; r < 4; r++) b1f[nft - 4][r] = -c[r];
        } else {
            float wv2 = Wv2[(nft - 8) * 16 + l16];
            #pragma unroll
            for (int r = 0; r < 4; r++) vacc[r] += fmaxf(-c[r], 0.f) * wv2;
        }
    }

    const float bv2v = bv2[0];
    #pragma unroll
    for (int r = 0; r < 4; r++) {
        float s = vacc[r];
        #pragma unroll
        for (int nf = 0; nf < 4; nf++) {
            float h = hid[nf][r] + b1f[nf][r];
            h = h > 0.f ? h : expm1f(h);
            s += h * wff[nf][r];
        }
        s += __shfl_xor(s, 1); s += __shfl_xor(s, 2);
        s += __shfl_xor(s, 4); s += __shfl_xor(s, 8);
        if (l16 == 0) q1[(size_t)32 * BT + bt * 16 + quad * 4 + r] = s + bv2v;
    }
}

// ---------------- K4: wc + final mix — single Ycn pass -------------------
__global__ __launch_bounds__(256) void k4_final(
    const float* __restrict__ qs, const float* __restrict__ Ycn,
    const float* __restrict__ q1, const float* __restrict__ Wv2,
    const float* __restrict__ bv2, float* __restrict__ out)
{
    const int bt = blockIdx.x;
    __shared__ float qs_s[16][33];
    __shared__ float qw_s[16][33];
    __shared__ float hidp[4][16][64];
    __shared__ float wfb[16][64], b1b[16][64], vb[16][64];

    const int t = threadIdx.x, w = t >> 6, lane = t & 63;
    const int quad = lane >> 4, l16 = lane & 15;
    const float bv2v = bv2[0];

    {
        int l = t * 2;
        float2 v = *(const float2*)&qs[(size_t)(bt * 16 + (l >> 5)) * NA + (l & 31)];
        qs_s[l >> 5][(l & 31) + 0] = v.x;
        qs_s[l >> 5][(l & 31) + 1] = v.y;
    }
    __syncthreads();

    {
        const int rr = w * 4 + quad;
        float qtv = q1[(size_t)32 * BT + bt * 16 + rr];
        float d0 = fabsf(qtv - q1[(size_t)(2 * l16 + 0) * BT + bt * 16 + rr]);
        float d1 = fabsf(qtv - q1[(size_t)(2 * l16 + 1) * BT + bt * 16 + rr]);
        float ss = d0 * d0 + d1 * d1;
        ss += __shfl_xor(ss, 1); ss += __shfl_xor(ss, 2);
        ss += __shfl_xor(ss, 4); ss += __shfl_xor(ss, 8);
        float inv = 1.f / fmaxf(sqrtf(ss), 1e-12f);
        qw_s[rr][2 * l16 + 0] = qs_s[rr][2 * l16 + 0] * d0 * inv;
        qw_s[rr][2 * l16 + 1] = qs_s[rr][2 * l16 + 1] * d1 * inv;
    }
    __syncthreads();

    const float* Yb = Ycn + (size_t)bt * NFRG * 256;

    floatx4 hid[4];
    #pragma unroll
    for (int nf = 0; nf < 4; nf++) hid[nf] = (floatx4)0.f;
    for (int ia = 0; ia < 8; ia++) {
        const int a = w * 8 + ia;
        const float* yp = Yb + (size_t)(a * 4) * 256 + lane * 4;
        float qv[4];
        #pragma unroll
        for (int r = 0; r < 4; r++) qv[r] = qw_s[quad * 4 + r][a];
        #pragma unroll
        for (int nf = 0; nf < 4; nf++) {
            floatx4 c = *(const floatx4*)(yp + nf * 256);   // c = -Y
            #pragma unroll
            for (int r = 0; r < 4; r++) hid[nf][r] += qv[r] * fabsf(c[r]);
        }
    }
    #pragma unroll
    for (int nf = 0; nf < 4; nf++)
        #pragma unroll
        for (int r = 0; r < 4; r++)
            hidp[w][quad * 4 + r][nf * 16 + l16] = hid[nf][r];

    #pragma unroll
    for (int fi = 0; fi < 3; fi++) {
        const int nft = w * 3 + fi;
        floatx4 c = *(const floatx4*)(Yb + (size_t)(128 + nft) * 256 + lane * 4);
        const int e = (nft & 3) * 16 + l16;
        #pragma unroll
        for (int r = 0; r < 4; r++) {
            int b = quad * 4 + r;
            if (nft < 4)      wfb[b][e] = fabsf(c[r]);
            else if (nft < 8) b1b[b][e] = -c[r];
            else              vb[b][e]  = fmaxf(-c[r], 0.f) * Wv2[e];
        }
    }
    __syncthreads();

    #pragma unroll
    for (int bb = 0; bb < 4; bb++) {
        int b = w * 4 + bb;
        float h = hidp[0][b][lane] + hidp[1][b][lane]
                + hidp[2][b][lane] + hidp[3][b][lane] + b1b[b][lane];
        h = h > 0.f ? h : expm1f(h);
        float val = h * wfb[b][lane] + vb[b][lane];
        #pragma unroll
        for (int off = 32; off > 0; off >>= 1) val += __shfl_xor(val, off);
        if (lane == 0) out[bt * 16 + b] = val + bv2v;
    }
}

extern "C" void kernel_launch(void* const* d_in, const int* in_sizes, int n_in,
                              void* d_out, int out_size, void* d_ws, size_t ws_size,
                              hipStream_t stream) {
    const float* qs  = (const float*)d_in[0];
    const float* st  = (const float*)d_in[1];
    const float* Ww1 = (const float*)d_in[2];
    const float* bw1 = (const float*)d_in[3];
    const float* Wwf = (const float*)d_in[4];
    const float* bwf = (const float*)d_in[5];
    const float* Wb1 = (const float*)d_in[6];
    const float* bb1 = (const float*)d_in[7];
    const float* Wv1 = (const float*)d_in[8];
    const float* bv1 = (const float*)d_in[9];
    const float* Wv2 = (const float*)d_in[10];
    const float* bv2 = (const float*)d_in[11];
    float* out = (float*)d_out;

    // workspace (~37 MB)
    float* Ycn           = (float*)d_ws;                           // 128*144*256 f32 = 18.87 MB
    unsigned short* stA  = (unsigned short*)(Ycn + (size_t)128 * NFRG * 256); // 8.39 MB
    unsigned short* Wswz = stA + (size_t)SD * SD;                  // 32*144*1024 bf16 = 9.44 MB
    float* bcat          = (float*)(Wswz + (size_t)32 * NFRG * 1024); // 2304 f32
    float* q1v           = bcat + NFRG * 16;                       // 33*2048 f32

    k0_ast <<<dim3(16, 128), 256, 0, stream>>>(st, stA);
    k0_wswz<<<dim3(NFRG / 2, 32), 256, 0, stream>>>(Ww1, Wwf, Wb1, Wv1,
                                                    bw1, bwf, bb1, bv1, Wswz, bcat);

    k1_gemm<<<dim3(BT / 64, NFRG / 8), 256, 0, stream>>>(stA, Wswz, bcat, Ycn);
    k3_qtot<<<BT / 16, 64, 0, stream>>>(qs, Wv2, bv2, Ycn, q1v);
    k3_q1  <<<dim3(NA, BT / 16), 64, 0, stream>>>(stA, qs, Wswz, Wv2, bv2, Ycn, q1v);
    k4_final<<<BT / 16, 256, 0, stream>>>(qs, Ycn, q1v, Wv2, bv2, out);
}